// Round 11
// baseline (25.305 us; speedup 1.0000x reference)
//
#include <hip/hip_runtime.h>
#include <cstdint>
#include <cmath>

#define N_WIRES 10
#define N_OPS 30
#define NG_SAFE 50
#define NG_MAX 50

typedef __attribute__((ext_vector_type(2))) float f2;   // (re, im) packed pair

// ---------------- compile-time numpy RandomState(42) replication -------------

struct CERng { uint32_t mt[624]; int mti; };

constexpr uint32_t ce_next32(CERng& r) {
  if (r.mti >= 624) {
    for (int i = 0; i < 624; ++i) {
      uint32_t y = (r.mt[i] & 0x80000000u) | (r.mt[(i + 1) % 624] & 0x7fffffffu);
      uint32_t v = r.mt[(i + 397) % 624] ^ (y >> 1);
      if (y & 1u) v ^= 2567483615u;
      r.mt[i] = v;
    }
    r.mti = 0;
  }
  uint32_t y = r.mt[r.mti++];
  y ^= y >> 11;
  y ^= (y << 7) & 2636928640u;
  y ^= (y << 15) & 4022730752u;
  y ^= y >> 18;
  return y;
}

constexpr uint32_t ce_masked(CERng& r, uint32_t rng) {  // legacy single-32b draw (R2-validated)
  if (rng == 0) return 0;
  uint32_t mask = rng;
  mask |= mask >> 1; mask |= mask >> 2; mask |= mask >> 4;
  mask |= mask >> 8; mask |= mask >> 16;
  uint32_t v = ce_next32(r) & mask;
  while (v > rng) v = ce_next32(r) & mask;
  return v;
}

struct RawSpec { int ty[N_OPS]; int w0[N_OPS]; int w1[N_OPS]; };

constexpr RawSpec make_raw() {
  RawSpec s{};
  CERng r{};
  r.mt[0] = 42u;
  for (int i = 1; i < 624; ++i)
    r.mt[i] = 1812433253u * (r.mt[i - 1] ^ (r.mt[i - 1] >> 30)) + (uint32_t)i;
  r.mti = 624;
  for (int k = 0; k < N_OPS; ++k) {
    int g = (int)ce_masked(r, 3u);
    if (g == 3) {
      int arr[N_WIRES] = {0,1,2,3,4,5,6,7,8,9};
      for (int i = N_WIRES - 1; i >= 1; --i) {
        int j = (int)ce_masked(r, (uint32_t)i);
        int t = arr[i]; arr[i] = arr[j]; arr[j] = t;
      }
      s.ty[k] = 3; s.w0[k] = arr[0]; s.w1[k] = arr[1];
    } else {
      s.ty[k] = g; s.w0[k] = (int)ce_masked(r, 9u); s.w1[k] = -1;
    }
  }
  return s;
}

constexpr RawSpec RAW = make_raw();

// ---------------- SAFE program (R9-proven, untransformed) --------------------
struct Full { int type[NG_MAX]; int p0[NG_MAX]; int p1[NG_MAX]; int aidx[NG_MAX]; int wbit[N_WIRES]; };

constexpr Full make_safe() {
  Full f{};
  int cost[N_WIRES] = {};
  for (int k = 0; k < N_OPS; ++k) {
    if (RAW.ty[k] == 3) { cost[RAW.w0[k]] += 1; cost[RAW.w1[k]] += 2; }
    else if (RAW.ty[k] != 2) cost[RAW.w0[k]] += 2;
  }
  for (int w = 0; w < N_WIRES; ++w) cost[w] += 2;
  int ord[N_WIRES] = {0,1,2,3,4,5,6,7,8,9};
  for (int i = 0; i < N_WIRES; ++i) {
    int best = i;
    for (int j = i + 1; j < N_WIRES; ++j)
      if (cost[ord[j]] > cost[ord[best]]) best = j;
    int t = ord[i]; ord[i] = ord[best]; ord[best] = t;
  }
  f.wbit[ord[0]] = 3; f.wbit[ord[1]] = 2; f.wbit[ord[2]] = 1; f.wbit[ord[3]] = 0;
  f.wbit[ord[4]] = 4; f.wbit[ord[5]] = 5;
  f.wbit[ord[6]] = 8; f.wbit[ord[7]] = 9;
  f.wbit[ord[8]] = 6; f.wbit[ord[9]] = 7;
  for (int k = 0; k < N_OPS; ++k) {
    f.type[k] = RAW.ty[k];
    if (RAW.ty[k] == 3) { f.p0[k] = f.wbit[RAW.w0[k]]; f.p1[k] = f.wbit[RAW.w1[k]]; f.aidx[k] = 0; }
    else                { f.p0[k] = f.wbit[RAW.w0[k]]; f.p1[k] = 0; f.aidx[k] = 10 + k; }
  }
  for (int w = 0; w < N_WIRES; ++w) {
    f.type[N_OPS + 2*w]     = 0; f.p0[N_OPS + 2*w]     = f.wbit[w]; f.p1[N_OPS + 2*w]     = 0; f.aidx[N_OPS + 2*w]     = 40;
    f.type[N_OPS + 2*w + 1] = 1; f.p0[N_OPS + 2*w + 1] = f.wbit[w]; f.p1[N_OPS + 2*w + 1] = 0; f.aidx[N_OPS + 2*w + 1] = 41;
  }
  return f;
}

constexpr Full FULLS = make_safe();

constexpr int s_wire_at_bit(int bp) {
  for (int w = 0; w < N_WIRES; ++w) if (FULLS.wbit[w] == bp) return w;
  return 0;
}
constexpr int SRW0 = s_wire_at_bit(0), SRW1 = s_wire_at_bit(1), SRW2 = s_wire_at_bit(2), SRW3 = s_wire_at_bit(3);
constexpr int SLW0 = s_wire_at_bit(4), SLW1 = s_wire_at_bit(5), SLW2 = s_wire_at_bit(6),
              SLW3 = s_wire_at_bit(7), SLW4 = s_wire_at_bit(8), SLW5 = s_wire_at_bit(9);

// ---------------- FAST program: Clifford-tracked, CNOT-free (R10-proven) -----

struct Prog {
  int nrot;
  int rty[N_OPS], raidx[N_OPS], rvs[N_OPS], rvl[N_OPS], rrs[N_OPS], rrl[N_OPS];
  int tvs[N_WIRES], tvl[N_WIRES], trs[N_WIRES], trl[N_WIRES];
  int mrs[N_WIRES], mrl[N_WIRES];
  int pos[N_WIRES];
  bool ok;
};

constexpr Prog make_prog() {
  Prog P{};
  P.ok = true;
  int phi[N_WIRES], pir[N_WIRES];
  for (int w = 0; w < N_WIRES; ++w) { phi[w] = 1 << w; pir[w] = 1 << w; }
  int n = 0;
  int gt[N_OPS] = {}, ga[N_OPS] = {}, gv[N_OPS] = {}, gr[N_OPS] = {};
  for (int k = 0; k < N_OPS; ++k) {
    if (RAW.ty[k] == 3) {
      const int c = RAW.w0[k], t = RAW.w1[k];
      phi[c] ^= phi[t];
      pir[t] ^= pir[c];
    } else {
      gt[n] = RAW.ty[k]; ga[n] = 10 + k;
      gv[n] = phi[RAW.w0[k]]; gr[n] = pir[RAW.w0[k]];
      ++n;
    }
  }
  P.nrot = n;
  for (int u = 0; u < N_WIRES; ++u)
    for (int v = 0; v < N_WIRES; ++v) {
      const int par = __builtin_popcount((unsigned)(pir[u] & phi[v])) & 1;
      if (par != (u == v ? 1 : 0)) P.ok = false;
    }
  int bestS = 15; long long bestC = (1LL << 60);
  for (int S = 0; S < 1024; ++S) {
    if (__builtin_popcount((unsigned)S) != 4) continue;
    long long c = 0;
    for (int i = 0; i < n; ++i)
      if (gt[i] != 2 && (gv[i] & ~S & 1023)) c += 32;
    for (int w = 0; w < N_WIRES; ++w)
      if (phi[w] & ~S & 1023) c += 32;
    if (c < bestC) { bestC = c; bestS = S; }
  }
  { int sp = 0;
    for (int w = 0; w < N_WIRES; ++w) if ((bestS >> w) & 1) P.pos[w] = sp++; }
  int freq[N_WIRES] = {};
  for (int i = 0; i < n; ++i)
    if (gt[i] != 2 && (gv[i] & ~bestS & 1023))
      for (int w = 0; w < N_WIRES; ++w)
        if (((gv[i] >> w) & 1) && !((bestS >> w) & 1)) freq[w]++;
  for (int w = 0; w < N_WIRES; ++w)
    if (phi[w] & ~bestS & 1023)
      for (int y = 0; y < N_WIRES; ++y)
        if (((phi[w] >> y) & 1) && !((bestS >> y) & 1)) freq[y]++;
  int minw = -1;
  for (int w = 0; w < N_WIRES; ++w)
    if (!((bestS >> w) & 1) && (minw < 0 || freq[w] < freq[minw])) minw = w;
  { int lp = 4;
    for (int w = 0; w < N_WIRES; ++w)
      if (!((bestS >> w) & 1)) { P.pos[w] = (w == minw) ? 9 : lp++; } }
  auto mp = [&](int m) {
    int r2 = 0;
    for (int w = 0; w < N_WIRES; ++w) if ((m >> w) & 1) r2 |= 1 << P.pos[w];
    return r2;
  };
  for (int i = 0; i < n; ++i) {
    const int v = mp(gv[i]), r2 = mp(gr[i]);
    P.rty[i] = gt[i]; P.raidx[i] = ga[i];
    P.rvs[i] = v & 15; P.rvl[i] = v >> 4;
    P.rrs[i] = r2 & 15; P.rrl[i] = r2 >> 4;
    if (v == 0 || r2 == 0) P.ok = false;
    if ((__builtin_popcount((unsigned)(v & r2)) & 1) == 0) P.ok = false;
  }
  for (int w = 0; w < N_WIRES; ++w) {
    const int v = mp(phi[w]), r2 = mp(pir[w]);
    P.tvs[w] = v & 15; P.tvl[w] = v >> 4;
    P.trs[w] = r2 & 15; P.trl[w] = r2 >> 4;
    P.mrs[w] = r2 & 15; P.mrl[w] = r2 >> 4;
    if (v == 0 || r2 == 0) P.ok = false;
    if ((__builtin_popcount((unsigned)(v & r2)) & 1) == 0) P.ok = false;
  }
  return P;
}

constexpr Prog PROG = make_prog();
static_assert(PROG.ok, "Clifford tracking invariant violated");

// --------------------------------- device ------------------------------------

struct Ctx { int lane; bool s16, s32; };
struct U2t { float ty, tx, A, s; };

__device__ inline f2 fswap(f2 v) { return __builtin_shufflevector(v, v, 1, 0); }

__device__ inline float bcast(float x, int l) {
  return __int_as_float(__builtin_amdgcn_readlane(__float_as_int(x), l));
}

// ---- DPP xor-exchange machinery: any mask 0..15 in <=3 pure-VALU ops --------
template <int CTRL>
__device__ inline float dppx(float x) {
  return __int_as_float(__builtin_amdgcn_update_dpp(0, __float_as_int(x), CTRL, 0xF, 0xF, true));
}
// quad_perm xor1=0xB1, xor2=0x4E, xor3=0x1B; row_half_mirror(xor7)=0x141; row_mirror(xor15)=0x140
template <int M>
__device__ inline float dpp_xor(float x) {
  static_assert(M >= 0 && M <= 15, "");
  if constexpr (M == 0) return x;
  else if constexpr (M == 1) return dppx<0xB1>(x);
  else if constexpr (M == 2) return dppx<0x4E>(x);
  else if constexpr (M == 3) return dppx<0x1B>(x);
  else if constexpr (M == 7) return dppx<0x141>(x);
  else if constexpr (M == 15) return dppx<0x140>(x);
  else if constexpr (M < 8) return dpp_xor<M ^ 7>(dppx<0x141>(x));    // 4,5,6
  else return dpp_xor<M ^ 15>(dppx<0x140>(x));                        // 8..14
}
constexpr int dpp_cost(int m) {
  if (m == 0) return 0;
  if (m == 1 || m == 2 || m == 3 || m == 7 || m == 15) return 1;
  if (m < 8) return 1 + dpp_cost(m ^ 7);
  return 1 + dpp_cost(m ^ 15);
}

// xor-exchange by mask 1..63.  VALU path (DPP/permlane) when cost<=3, else
// permlane32 (if bit5) + single ds_swizzle for the low 5 bits.
template <int VL>
__device__ inline float lxf(float x, const Ctx& cx) {
  static_assert(VL >= 1 && VL <= 63, "");
  constexpr int lo = VL & 15;
  constexpr bool b16 = (VL & 16) != 0;
  constexpr bool b32 = (VL & 32) != 0;
  constexpr int vcost = dpp_cost(lo) + (b16 ? 2 : 0) + (b32 ? 2 : 0);
  if constexpr (vcost <= 3) {
    float t = x;
    if constexpr (b32) {
#if __has_builtin(__builtin_amdgcn_permlane32_swap)
      auto r = __builtin_amdgcn_permlane32_swap(__float_as_int(t), __float_as_int(t), false, false);
      t = __int_as_float(cx.s32 ? r[0] : r[1]);
#else
      t = __shfl_xor(t, 32, 64);
#endif
    }
    if constexpr (b16) {
#if __has_builtin(__builtin_amdgcn_permlane16_swap)
      auto r = __builtin_amdgcn_permlane16_swap(__float_as_int(t), __float_as_int(t), false, false);
      t = __int_as_float(cx.s16 ? r[0] : r[1]);
#else
      t = __shfl_xor(t, 16, 64);
#endif
    }
    return dpp_xor<lo>(t);
  } else {
    float t = x;
    if constexpr (b32) {
#if __has_builtin(__builtin_amdgcn_permlane32_swap)
      auto r = __builtin_amdgcn_permlane32_swap(__float_as_int(t), __float_as_int(t), false, false);
      t = __int_as_float(cx.s32 ? r[0] : r[1]);
#else
      t = __shfl_xor(t, 32, 64);
#endif
    }
    if constexpr ((VL & 31) != 0)
      t = __int_as_float(__builtin_amdgcn_ds_swizzle(__float_as_int(t), ((VL & 31) << 10) | 0x1F));
    return t;
  }
}
template <int VL>
__device__ inline f2 lxf2(f2 v, const Ctx& cx) {
  f2 r; r.x = lxf<VL>(v.x, cx); r.y = lxf<VL>(v.y, cx); return r;
}

// SAFE exchange
template <int M>
__device__ inline float sshfl(float x) { return __shfl_xor(x, M, 64); }
template <int M>
__device__ inline f2 sshfl2(f2 v) { f2 r; r.x = sshfl<M>(v.x); r.y = sshfl<M>(v.y); return r; }

template <int RL>
__device__ inline bool lpar6(const bool (&lb)[6]) {
  bool p = false;
  if constexpr (RL & 1)  p ^= lb[0];
  if constexpr (RL & 2)  p ^= lb[1];
  if constexpr (RL & 4)  p ^= lb[2];
  if constexpr (RL & 8)  p ^= lb[3];
  if constexpr (RL & 16) p ^= lb[4];
  if constexpr (RL & 32) p ^= lb[5];
  return p;
}

// ---------------- FAST gates: tau-form with generalized xor-masks ------------

template <int TY, int VS, int VL, int RS, int RL>
__device__ inline void rot_fast(f2 (&st)[16], float tau, const Ctx& cx, const bool (&lb)[6]) {
  if constexpr (TY == 2) {            // RZ
    const bool lp_ = lpar6<RL>(lb);
    const f2 tn = {tau, -tau}, tnn = {-tau, tau};
    const f2 tA = lp_ ? tnn : tn;
    const f2 tB = lp_ ? tn : tnn;
    #pragma unroll
    for (int j = 0; j < 16; ++j) {
      const f2 t = (__builtin_popcount((unsigned)(j & RS)) & 1) ? tB : tA;
      st[j] = st[j] + t * fswap(st[j]);
    }
  } else if constexpr (TY == 0) {     // RX
    const f2 tn = {tau, -tau};
    #pragma unroll
    for (int j = 0; j < 16; ++j) {
      if constexpr (VS != 0) { if (j & (VS & -VS)) continue; }
      const int j2 = j ^ VS;
      f2 pj, pj2;
      if constexpr (VL != 0) {
        pj = lxf2<VL>(st[j2], cx);
        if constexpr (VS != 0) pj2 = lxf2<VL>(st[j], cx);
      } else { pj = st[j2]; pj2 = st[j]; }
      st[j] = st[j] + tn * fswap(pj);
      if constexpr (VS != 0) st[j2] = st[j2] + tn * fswap(pj2);
    }
  } else {                            // RY
    const bool lp_ = lpar6<RL>(lb);
    const f2 tp = {tau, tau}, tm = {-tau, -tau};
    const f2 sA = lp_ ? tp : tm;
    const f2 sB = lp_ ? tm : tp;
    #pragma unroll
    for (int j = 0; j < 16; ++j) {
      if constexpr (VS != 0) { if (j & (VS & -VS)) continue; }
      const int j2 = j ^ VS;
      f2 pj, pj2;
      if constexpr (VL != 0) {
        pj = lxf2<VL>(st[j2], cx);
        if constexpr (VS != 0) pj2 = lxf2<VL>(st[j], cx);
      } else { pj = st[j2]; pj2 = st[j]; }
      const f2 s1 = (__builtin_popcount((unsigned)(j & RS)) & 1) ? sB : sA;
      st[j] = st[j] + s1 * pj;
      if constexpr (VS != 0) {
        const f2 s2_ = (__builtin_popcount((unsigned)(j2 & RS)) & 1) ? sB : sA;
        st[j2] = st[j2] + s2_ * pj2;
      }
    }
  }
}

template <int VS, int VL, int RS, int RL>
__device__ inline void tail_fast(f2 (&st)[16], const U2t& u, const Ctx& cx, const bool (&lb)[6]) {
  const bool lp_ = lpar6<RL>(lb);
  const f2 TpP = {u.ty, u.ty}, TpM = {-u.ty, -u.ty};
  const f2 TsP = {u.A, -u.A},  TsM = {-u.A, u.A};
  const f2 Xs  = {u.tx, -u.tx};
  const f2 TpA = lp_ ? TpP : TpM, TpB = lp_ ? TpM : TpP;
  const f2 TsA = lp_ ? TsP : TsM, TsB = lp_ ? TsM : TsP;
  #pragma unroll
  for (int j = 0; j < 16; ++j) {
    if constexpr (VS != 0) { if (j & (VS & -VS)) continue; }
    const int j2 = j ^ VS;
    f2 pj, pj2;
    if constexpr (VL != 0) {
      pj = lxf2<VL>(st[j2], cx);
      if constexpr (VS != 0) pj2 = lxf2<VL>(st[j], cx);
    } else { pj = st[j2]; pj2 = st[j]; }
    {
      const bool sp = __builtin_popcount((unsigned)(j & RS)) & 1;
      const f2 a = st[j];
      f2 o = a + (sp ? TpB : TpA) * pj;
      o = o + (sp ? TsB : TsA) * fswap(a);
      o = o + Xs * fswap(pj);
      st[j] = o;
    }
    if constexpr (VS != 0) {
      const bool sp = __builtin_popcount((unsigned)(j2 & RS)) & 1;
      const f2 a = st[j2];
      f2 o = a + (sp ? TpB : TpA) * pj2;
      o = o + (sp ? TsB : TsA) * fswap(a);
      o = o + Xs * fswap(pj2);
      st[j2] = o;
    }
  }
}

template <int K>
__device__ inline void run_rot(f2 (&st)[16], float tc, float ts, const Ctx& cx,
                               float& scale, const bool (&lb)[6]) {
  if constexpr (K < N_OPS) {
    if constexpr (K < PROG.nrot) {
      const float c = bcast(tc, PROG.raidx[K]);
      const float s = bcast(ts, PROG.raidx[K]);
      const float tau = s * __builtin_amdgcn_rcpf(c);
      scale *= c;
      rot_fast<PROG.rty[K], PROG.rvs[K], PROG.rvl[K], PROG.rrs[K], PROG.rrl[K]>(st, tau, cx, lb);
      run_rot<K + 1>(st, tc, ts, cx, scale, lb);
    }
  }
}

template <int W>
__device__ inline void run_tail(f2 (&st)[16], const U2t& u, const Ctx& cx,
                                float& scale, const bool (&lb)[6]) {
  if constexpr (W < N_WIRES) {
    scale *= u.s;
    tail_fast<PROG.tvs[W], PROG.tvl[W], PROG.trs[W], PROG.trl[W]>(st, u, cx, lb);
    run_tail<W + 1>(st, u, cx, scale, lb);
  }
}

template <int W>
__device__ inline void enc_lane(float& lp, const bool (&lb)[6], const float (&ec)[10], const float (&es)[10]) {
  if constexpr (W < N_WIRES) {
    if constexpr (PROG.pos[W] >= 4)
      lp *= lb[PROG.pos[W] - 4] ? es[W] : ec[W];
    enc_lane<W + 1>(lp, lb, ec, es);
  }
}
template <int W>
__device__ inline void enc_slot(float& a, int j, const float (&ec)[10], const float (&es)[10]) {
  if constexpr (W < N_WIRES) {
    if constexpr (PROG.pos[W] < 4)
      a *= ((j >> PROG.pos[W]) & 1) ? es[W] : ec[W];
    enc_slot<W + 1>(a, j, ec, es);
  }
}
template <int W>
__device__ inline void head_lane(float (&h2)[10], const bool (&lb)[6], const float (&hwv)[10]) {
  if constexpr (W < N_WIRES) {
    const bool lp_ = lpar6<PROG.mrl[W]>(lb);
    h2[W] = lp_ ? -hwv[W] : hwv[W];
    head_lane<W + 1>(h2, lb, hwv);
  }
}
template <int W>
__device__ inline void head_shared(float& L, const float (&h2)[10]) {
  if constexpr (W < N_WIRES) {
    if constexpr (PROG.mrs[W] == 0) L += h2[W];
    head_shared<W + 1>(L, h2);
  }
}
template <int W>
__device__ inline void head_slot(float& sw, int j, const float (&h2)[10]) {
  if constexpr (W < N_WIRES) {
    if constexpr (PROG.mrs[W] != 0)
      sw += (__builtin_popcount((unsigned)(j & PROG.mrs[W])) & 1) ? -h2[W] : h2[W];
    head_slot<W + 1>(sw, j, h2);
  }
}

__device__ inline void body_fast(const Ctx& cx, int b, float tc, float ts,
                                 const float* __restrict__ hw, const float* __restrict__ hb,
                                 float* __restrict__ out) {
  const int lane = cx.lane;
  const bool lb[6] = { (bool)((lane >> 0) & 1), (bool)((lane >> 1) & 1), (bool)((lane >> 2) & 1),
                       (bool)((lane >> 3) & 1), (bool)((lane >> 4) & 1), (bool)((lane >> 5) & 1) };
  U2t u;
  {
    const float cxr = bcast(tc, 40), sxr = bcast(ts, 40);
    const float cyr = bcast(tc, 41), syr = bcast(ts, 41);
    u.tx = sxr * __builtin_amdgcn_rcpf(cxr);
    u.ty = syr * __builtin_amdgcn_rcpf(cyr);
    u.A = u.ty * u.tx;
    u.s = cyr * cxr;
  }
  float ec[10], es[10];
  #pragma unroll
  for (int w = 0; w < N_WIRES; ++w) { ec[w] = bcast(tc, w); es[w] = bcast(ts, w); }
  float lpv = 1.0f;
  enc_lane<0>(lpv, lb, ec, es);
  f2 st[16];
  #pragma unroll
  for (int j = 0; j < 16; ++j) {
    float a = lpv;
    enc_slot<0>(a, j, ec, es);
    st[j] = (f2){a, 0.0f};
  }

  float scale = 1.0f;
  run_rot<0>(st, tc, ts, cx, scale, lb);
  run_tail<0>(st, u, cx, scale, lb);

  float hwv[10];
  #pragma unroll
  for (int w = 0; w < N_WIRES; ++w) hwv[w] = hw[w];
  float h2[10];
  head_lane<0>(h2, lb, hwv);
  float L = 0.0f;
  head_shared<0>(L, h2);
  float acc = 0.0f;
  #pragma unroll
  for (int j = 0; j < 16; ++j) {
    float sw = L;
    head_slot<0>(sw, j, h2);
    const f2 q = st[j] * st[j];
    acc += (q.x + q.y) * sw;
  }
  acc *= scale * scale;
  acc += lxf<1>(acc, cx);
  acc += lxf<2>(acc, cx);
  acc += lxf<4>(acc, cx);
  acc += lxf<8>(acc, cx);
  acc += lxf<16>(acc, cx);
  acc += lxf<32>(acc, cx);
  if (lane == 0) {
    const float logit = acc + hb[0] + 1.57079632679489662f;  // + SHIFT
    out[b] = 1.0f / (1.0f + expf(-logit));
  }
}

// ---------------- SAFE path (R9-proven) --------------------------------------

template <int TY, int P>
__device__ inline void gate_local_cs(f2 (&st)[16], float c, float s) {
  const f2 c2 = {c, c}, s2 = {s, s}, sn = {s, -s};
  #pragma unroll
  for (int b = 0; b < 16; ++b) {
    if ((b >> P) & 1) continue;
    const int i0 = b, i1 = b | (1 << P);
    const f2 a0 = st[i0], a1 = st[i1];
    if constexpr (TY == 0) {
      st[i0] = c2 * a0 + sn * fswap(a1);
      st[i1] = c2 * a1 + sn * fswap(a0);
    } else if constexpr (TY == 1) {
      st[i0] = c2 * a0 - s2 * a1;
      st[i1] = c2 * a1 + s2 * a0;
    } else {
      st[i0] = c2 * a0 + sn * fswap(a0);
      st[i1] = c2 * a1 - sn * fswap(a1);
    }
  }
}

template <int TY, int LB>
__device__ inline void gate_lane_cs(f2 (&st)[16], float c, float s, int lane) {
  const f2 c2 = {c, c};
  if constexpr (TY == 2) {
    const float t = ((lane >> LB) & 1) ? -s : s;
    const f2 tn = {t, -t};
    #pragma unroll
    for (int j = 0; j < 16; ++j) st[j] = c2 * st[j] + tn * fswap(st[j]);
  } else if constexpr (TY == 0) {
    const f2 sn = {s, -s};
    #pragma unroll
    for (int j = 0; j < 16; ++j) {
      const f2 p = sshfl2<(1 << LB)>(st[j]);
      st[j] = c2 * st[j] + sn * fswap(p);
    }
  } else {
    const float sg = ((lane >> LB) & 1) ? s : -s;
    const f2 sg2 = {sg, sg};
    #pragma unroll
    for (int j = 0; j < 16; ++j) {
      const f2 p = sshfl2<(1 << LB)>(st[j]);
      st[j] = c2 * st[j] + sg2 * p;
    }
  }
}

template <int CB, int TB>
__device__ inline void cnot_safe(f2 (&st)[16], int lane) {
  if constexpr (CB < 4 && TB < 4) {
    #pragma unroll
    for (int b = 0; b < 16; ++b) {
      if (((b >> CB) & 1) && !((b >> TB) & 1)) {
        const int j = b | (1 << TB);
        const f2 t = st[b]; st[b] = st[j]; st[j] = t;
      }
    }
  } else if constexpr (CB < 4) {
    constexpr int M = 1 << (TB - 4);
    #pragma unroll
    for (int b = 0; b < 16; ++b) {
      if ((b >> CB) & 1) st[b] = sshfl2<M>(st[b]);
    }
  } else if constexpr (TB < 4) {
    const bool cb = (lane >> (CB - 4)) & 1;
    #pragma unroll
    for (int b = 0; b < 16; ++b) {
      if (!((b >> TB) & 1)) {
        const int j = b | (1 << TB);
        const f2 a0 = st[b], a1 = st[j];
        st[b] = cb ? a1 : a0; st[j] = cb ? a0 : a1;
      }
    }
  } else {
    const bool cb = (lane >> (CB - 4)) & 1;
    constexpr int M = 1 << (TB - 4);
    #pragma unroll
    for (int j = 0; j < 16; ++j) {
      const f2 p = sshfl2<M>(st[j]);
      st[j] = cb ? p : st[j];
    }
  }
}

template <int K>
__device__ inline void run_safe(f2 (&st)[16], float tc, float ts, int lane) {
  if constexpr (K < NG_SAFE) {
    constexpr int ty = FULLS.type[K];
    constexpr int P0 = FULLS.p0[K];
    constexpr int P1 = FULLS.p1[K];
    constexpr int AI = FULLS.aidx[K];
    if constexpr (ty == 3) {
      cnot_safe<P0, P1>(st, lane);
    } else {
      const float c = __shfl(tc, AI, 64);
      const float s = __shfl(ts, AI, 64);
      if constexpr (P0 < 4) gate_local_cs<ty, P0>(st, c, s);
      else                  gate_lane_cs<ty, P0 - 4>(st, c, s, lane);
    }
    run_safe<K + 1>(st, tc, ts, lane);
  }
}

__device__ __attribute__((noinline))
void body_safe(int lane, int b, float tc, float ts,
               const float* __restrict__ hw, const float* __restrict__ hb,
               float* __restrict__ out) {
  float ec[N_WIRES], es[N_WIRES];
  #pragma unroll
  for (int w = 0; w < N_WIRES; ++w) { ec[w] = __shfl(tc, w, 64); es[w] = __shfl(ts, w, 64); }
  float lp = ((lane >> 0) & 1) ? es[SLW0] : ec[SLW0];
  lp *= ((lane >> 1) & 1) ? es[SLW1] : ec[SLW1];
  lp *= ((lane >> 2) & 1) ? es[SLW2] : ec[SLW2];
  lp *= ((lane >> 3) & 1) ? es[SLW3] : ec[SLW3];
  lp *= ((lane >> 4) & 1) ? es[SLW4] : ec[SLW4];
  lp *= ((lane >> 5) & 1) ? es[SLW5] : ec[SLW5];
  f2 st[16];
  #pragma unroll
  for (int sl = 0; sl < 16; ++sl) {
    float a = lp;
    a *= (sl & 1) ? es[SRW0] : ec[SRW0];
    a *= (sl & 2) ? es[SRW1] : ec[SRW1];
    a *= (sl & 4) ? es[SRW2] : ec[SRW2];
    a *= (sl & 8) ? es[SRW3] : ec[SRW3];
    st[sl] = (f2){a, 0.0f};
  }
  run_safe<0>(st, tc, ts, lane);
  float hwv[N_WIRES];
  #pragma unroll
  for (int w = 0; w < N_WIRES; ++w) hwv[w] = hw[w];
  float lw = (((lane >> 0) & 1) ? -hwv[SLW0] : hwv[SLW0])
           + (((lane >> 1) & 1) ? -hwv[SLW1] : hwv[SLW1])
           + (((lane >> 2) & 1) ? -hwv[SLW2] : hwv[SLW2])
           + (((lane >> 3) & 1) ? -hwv[SLW3] : hwv[SLW3])
           + (((lane >> 4) & 1) ? -hwv[SLW4] : hwv[SLW4])
           + (((lane >> 5) & 1) ? -hwv[SLW5] : hwv[SLW5]);
  float acc = 0.0f;
  #pragma unroll
  for (int sl = 0; sl < 16; ++sl) {
    float sw = lw;
    sw += (sl & 1) ? -hwv[SRW0] : hwv[SRW0];
    sw += (sl & 2) ? -hwv[SRW1] : hwv[SRW1];
    sw += (sl & 4) ? -hwv[SRW2] : hwv[SRW2];
    sw += (sl & 8) ? -hwv[SRW3] : hwv[SRW3];
    const f2 q = st[sl] * st[sl];
    acc += (q.x + q.y) * sw;
  }
  acc += sshfl<1>(acc);
  acc += sshfl<2>(acc);
  acc += sshfl<4>(acc);
  acc += sshfl<8>(acc);
  acc += sshfl<16>(acc);
  acc += sshfl<32>(acc);
  if (lane == 0) {
    const float logit = acc + hb[0] + 1.57079632679489662f;
    out[b] = 1.0f / (1.0f + expf(-logit));
  }
}

// ---------------------------------- kernel -----------------------------------

__global__ __launch_bounds__(256)
void qsim_kernel(const float* __restrict__ xb, const float* __restrict__ rxt,
                 const float* __restrict__ ryt, const float* __restrict__ rp,
                 const float* __restrict__ hw, const float* __restrict__ hb,
                 float* __restrict__ out, int bsz) {
  const int lane = threadIdx.x & 63;
  const int b = blockIdx.x * 4 + (threadIdx.x >> 6);  // one wave = one sample
  if (b >= bsz) return;

  float tc, ts;
  {
    float t = 0.0f;
    if (lane < 10)        t = xb[(size_t)b * 10 + lane];
    else if (lane < 40)   t = rp[lane - 10];
    else if (lane == 40)  t = rxt[0];
    else if (lane == 41)  t = ryt[0];
    float s, c;
    sincosf(0.5f * t, &s, &c);
    tc = c; ts = s;
  }

  // ---- mechanism self-test: every exchange class the fast path can use ----
  Ctx cx; cx.lane = lane; cx.s16 = false; cx.s32 = false;
#if __has_builtin(__builtin_amdgcn_permlane16_swap)
  {
    auto r = __builtin_amdgcn_permlane16_swap(lane, lane, false, false);
    const bool f16 = (((lane & 16) ? r[0] : r[1]) != (lane ^ 16));
    cx.s16 = (((lane & 16) != 0) ^ f16);
  }
#endif
#if __has_builtin(__builtin_amdgcn_permlane32_swap)
  {
    auto r = __builtin_amdgcn_permlane32_swap(lane, lane, false, false);
    const bool f32 = (((lane & 32) ? r[0] : r[1]) != (lane ^ 32));
    cx.s32 = (((lane & 32) != 0) ^ f32);
  }
#endif
  bool ok = true;
  ok &= (__float_as_int(lxf<1 >(__int_as_float(lane), cx)) == (lane ^ 1));   // qp1
  ok &= (__float_as_int(lxf<2 >(__int_as_float(lane), cx)) == (lane ^ 2));   // qp2
  ok &= (__float_as_int(lxf<3 >(__int_as_float(lane), cx)) == (lane ^ 3));   // qp3
  ok &= (__float_as_int(lxf<7 >(__int_as_float(lane), cx)) == (lane ^ 7));   // half_mirror
  ok &= (__float_as_int(lxf<9 >(__int_as_float(lane), cx)) == (lane ^ 9));   // 3-chain DPP
  ok &= (__float_as_int(lxf<15>(__int_as_float(lane), cx)) == (lane ^ 15));  // mirror
  ok &= (__float_as_int(lxf<16>(__int_as_float(lane), cx)) == (lane ^ 16));  // permlane16
  ok &= (__float_as_int(lxf<19>(__int_as_float(lane), cx)) == (lane ^ 19));  // pl16 + qp3
  ok &= (__float_as_int(lxf<21>(__int_as_float(lane), cx)) == (lane ^ 21));  // ds_swizzle
  ok &= (__float_as_int(lxf<32>(__int_as_float(lane), cx)) == (lane ^ 32));  // permlane32
  ok &= (__float_as_int(lxf<35>(__int_as_float(lane), cx)) == (lane ^ 35));  // pl32 + qp3
  ok &= (__float_as_int(lxf<53>(__int_as_float(lane), cx)) == (lane ^ 53));  // pl32 + swizzle
  const bool fast = (__all((int)ok) != 0);

  if (fast) body_fast(cx, b, tc, ts, hw, hb, out);
  else      body_safe(lane, b, tc, ts, hw, hb, out);
}

// ---------------------------------- launch -----------------------------------

extern "C" void kernel_launch(void* const* d_in, const int* in_sizes, int n_in,
                              void* d_out, int out_size, void* d_ws, size_t ws_size,
                              hipStream_t stream) {
  const float* xb  = (const float*)d_in[0];
  const float* rxt = (const float*)d_in[1];
  const float* ryt = (const float*)d_in[2];
  const float* rp  = (const float*)d_in[3];
  const float* hw  = (const float*)d_in[4];
  const float* hb  = (const float*)d_in[5];
  float* out = (float*)d_out;

  const int bsz = in_sizes[0] / N_WIRES;
  const int nblk = (bsz + 3) / 4;

  hipLaunchKernelGGL(qsim_kernel, dim3(nblk), dim3(256), 0, stream,
                     xb, rxt, ryt, rp, hw, hb, out, bsz);
}

// Round 12
// 19.298 us; speedup vs baseline: 1.3112x; 1.3112x over previous
//
#include <hip/hip_runtime.h>
#include <cstdint>
#include <cmath>

#define N_WIRES 10
#define N_OPS 30
#define NG_SAFE 50
#define NG_MAX 50

typedef __attribute__((ext_vector_type(2))) float f2;   // (re, im) packed pair

// ---------------- compile-time numpy RandomState(42) replication -------------

struct CERng { uint32_t mt[624]; int mti; };

constexpr uint32_t ce_next32(CERng& r) {
  if (r.mti >= 624) {
    for (int i = 0; i < 624; ++i) {
      uint32_t y = (r.mt[i] & 0x80000000u) | (r.mt[(i + 1) % 624] & 0x7fffffffu);
      uint32_t v = r.mt[(i + 397) % 624] ^ (y >> 1);
      if (y & 1u) v ^= 2567483615u;
      r.mt[i] = v;
    }
    r.mti = 0;
  }
  uint32_t y = r.mt[r.mti++];
  y ^= y >> 11;
  y ^= (y << 7) & 2636928640u;
  y ^= (y << 15) & 4022730752u;
  y ^= y >> 18;
  return y;
}

constexpr uint32_t ce_masked(CERng& r, uint32_t rng) {  // legacy single-32b draw (R2-validated)
  if (rng == 0) return 0;
  uint32_t mask = rng;
  mask |= mask >> 1; mask |= mask >> 2; mask |= mask >> 4;
  mask |= mask >> 8; mask |= mask >> 16;
  uint32_t v = ce_next32(r) & mask;
  while (v > rng) v = ce_next32(r) & mask;
  return v;
}

struct RawSpec { int ty[N_OPS]; int w0[N_OPS]; int w1[N_OPS]; };

constexpr RawSpec make_raw() {
  RawSpec s{};
  CERng r{};
  r.mt[0] = 42u;
  for (int i = 1; i < 624; ++i)
    r.mt[i] = 1812433253u * (r.mt[i - 1] ^ (r.mt[i - 1] >> 30)) + (uint32_t)i;
  r.mti = 624;
  for (int k = 0; k < N_OPS; ++k) {
    int g = (int)ce_masked(r, 3u);
    if (g == 3) {
      int arr[N_WIRES] = {0,1,2,3,4,5,6,7,8,9};
      for (int i = N_WIRES - 1; i >= 1; --i) {
        int j = (int)ce_masked(r, (uint32_t)i);
        int t = arr[i]; arr[i] = arr[j]; arr[j] = t;
      }
      s.ty[k] = 3; s.w0[k] = arr[0]; s.w1[k] = arr[1];
    } else {
      s.ty[k] = g; s.w0[k] = (int)ce_masked(r, 9u); s.w1[k] = -1;
    }
  }
  return s;
}

constexpr RawSpec RAW = make_raw();

// ---------------- SAFE program (R9-proven, untransformed) --------------------
struct Full { int type[NG_MAX]; int p0[NG_MAX]; int p1[NG_MAX]; int aidx[NG_MAX]; int wbit[N_WIRES]; };

constexpr Full make_safe() {
  Full f{};
  int cost[N_WIRES] = {};
  for (int k = 0; k < N_OPS; ++k) {
    if (RAW.ty[k] == 3) { cost[RAW.w0[k]] += 1; cost[RAW.w1[k]] += 2; }
    else if (RAW.ty[k] != 2) cost[RAW.w0[k]] += 2;
  }
  for (int w = 0; w < N_WIRES; ++w) cost[w] += 2;
  int ord[N_WIRES] = {0,1,2,3,4,5,6,7,8,9};
  for (int i = 0; i < N_WIRES; ++i) {
    int best = i;
    for (int j = i + 1; j < N_WIRES; ++j)
      if (cost[ord[j]] > cost[ord[best]]) best = j;
    int t = ord[i]; ord[i] = ord[best]; ord[best] = t;
  }
  f.wbit[ord[0]] = 3; f.wbit[ord[1]] = 2; f.wbit[ord[2]] = 1; f.wbit[ord[3]] = 0;
  f.wbit[ord[4]] = 4; f.wbit[ord[5]] = 5;
  f.wbit[ord[6]] = 8; f.wbit[ord[7]] = 9;
  f.wbit[ord[8]] = 6; f.wbit[ord[9]] = 7;
  for (int k = 0; k < N_OPS; ++k) {
    f.type[k] = RAW.ty[k];
    if (RAW.ty[k] == 3) { f.p0[k] = f.wbit[RAW.w0[k]]; f.p1[k] = f.wbit[RAW.w1[k]]; f.aidx[k] = 0; }
    else                { f.p0[k] = f.wbit[RAW.w0[k]]; f.p1[k] = 0; f.aidx[k] = 10 + k; }
  }
  for (int w = 0; w < N_WIRES; ++w) {
    f.type[N_OPS + 2*w]     = 0; f.p0[N_OPS + 2*w]     = f.wbit[w]; f.p1[N_OPS + 2*w]     = 0; f.aidx[N_OPS + 2*w]     = 40;
    f.type[N_OPS + 2*w + 1] = 1; f.p0[N_OPS + 2*w + 1] = f.wbit[w]; f.p1[N_OPS + 2*w + 1] = 0; f.aidx[N_OPS + 2*w + 1] = 41;
  }
  return f;
}

constexpr Full FULLS = make_safe();

constexpr int s_wire_at_bit(int bp) {
  for (int w = 0; w < N_WIRES; ++w) if (FULLS.wbit[w] == bp) return w;
  return 0;
}
constexpr int SRW0 = s_wire_at_bit(0), SRW1 = s_wire_at_bit(1), SRW2 = s_wire_at_bit(2), SRW3 = s_wire_at_bit(3);
constexpr int SLW0 = s_wire_at_bit(4), SLW1 = s_wire_at_bit(5), SLW2 = s_wire_at_bit(6),
              SLW3 = s_wire_at_bit(7), SLW4 = s_wire_at_bit(8), SLW5 = s_wire_at_bit(9);

// ---------------- FAST program: Clifford-tracked, CNOT-free ------------------
// amp_logical[i] = st[Phi i].  CNOT(c,t): Phi'=Phi*g (col c ^= col t),
// Phi'^-1 = g*Phi^-1 (row t ^= row c).  Rotation on wire w: xor-vector
// v = Phi col w; side(p) = parity(p & r), r = Phi^-1 row w.

struct Prog {
  int nrot;
  int rty[N_OPS], raidx[N_OPS], rvs[N_OPS], rvl[N_OPS], rrs[N_OPS], rrl[N_OPS];
  int tvs[N_WIRES], tvl[N_WIRES], trs[N_WIRES], trl[N_WIRES];
  int mrs[N_WIRES], mrl[N_WIRES];
  int pos[N_WIRES];            // wire -> physical bit (0..3 slot, 4..9 lane)
  bool ok;
};

constexpr Prog make_prog() {
  Prog P{};
  P.ok = true;
  int phi[N_WIRES], pir[N_WIRES];
  for (int w = 0; w < N_WIRES; ++w) { phi[w] = 1 << w; pir[w] = 1 << w; }
  int n = 0;
  int gt[N_OPS] = {}, ga[N_OPS] = {}, gv[N_OPS] = {}, gr[N_OPS] = {};
  for (int k = 0; k < N_OPS; ++k) {
    if (RAW.ty[k] == 3) {
      const int c = RAW.w0[k], t = RAW.w1[k];
      phi[c] ^= phi[t];        // Phi columns
      pir[t] ^= pir[c];        // Phi^-1 rows
    } else {
      gt[n] = RAW.ty[k]; ga[n] = 10 + k;
      gv[n] = phi[RAW.w0[k]]; gr[n] = pir[RAW.w0[k]];
      ++n;
    }
  }
  P.nrot = n;
  // validate Phi * Phi^-1 == I  (parity(pir[u] & phi[v]) == delta_uv)
  for (int u = 0; u < N_WIRES; ++u)
    for (int v = 0; v < N_WIRES; ++v) {
      const int par = __builtin_popcount((unsigned)(pir[u] & phi[v])) & 1;
      if (par != (u == v ? 1 : 0)) P.ok = false;
    }
  // choose 4 slot bits minimizing lane-crossing gates (exhaustive over C(10,4))
  int bestS = 15; long long bestC = (1LL << 60);
  for (int S = 0; S < 1024; ++S) {
    if (__builtin_popcount((unsigned)S) != 4) continue;
    long long c = 0;
    for (int i = 0; i < n; ++i)
      if (gt[i] != 2 && (gv[i] & ~S & 1023)) c += 32;
    for (int w = 0; w < N_WIRES; ++w)
      if (phi[w] & ~S & 1023) c += 32;
    if (c < bestC) { bestC = c; bestS = S; }
  }
  { int sp = 0;
    for (int w = 0; w < N_WIRES; ++w) if ((bestS >> w) & 1) P.pos[w] = sp++; }
  // lane wires: least-frequent (in crossing masks) gets physical bit 9 (permlane32)
  int freq[N_WIRES] = {};
  for (int i = 0; i < n; ++i)
    if (gt[i] != 2 && (gv[i] & ~bestS & 1023))
      for (int w = 0; w < N_WIRES; ++w)
        if (((gv[i] >> w) & 1) && !((bestS >> w) & 1)) freq[w]++;
  for (int w = 0; w < N_WIRES; ++w)
    if (phi[w] & ~bestS & 1023)
      for (int y = 0; y < N_WIRES; ++y)
        if (((phi[w] >> y) & 1) && !((bestS >> y) & 1)) freq[y]++;
  int minw = -1;
  for (int w = 0; w < N_WIRES; ++w)
    if (!((bestS >> w) & 1) && (minw < 0 || freq[w] < freq[minw])) minw = w;
  { int lp = 4;
    for (int w = 0; w < N_WIRES; ++w)
      if (!((bestS >> w) & 1)) { P.pos[w] = (w == minw) ? 9 : lp++; } }
  // map all masks through pos[]
  auto mp = [&](int m) {
    int r2 = 0;
    for (int w = 0; w < N_WIRES; ++w) if ((m >> w) & 1) r2 |= 1 << P.pos[w];
    return r2;
  };
  for (int i = 0; i < n; ++i) {
    const int v = mp(gv[i]), r2 = mp(gr[i]);
    P.rty[i] = gt[i]; P.raidx[i] = ga[i];
    P.rvs[i] = v & 15; P.rvl[i] = v >> 4;
    P.rrs[i] = r2 & 15; P.rrl[i] = r2 >> 4;
    if (v == 0 || r2 == 0) P.ok = false;
    if ((__builtin_popcount((unsigned)(v & r2)) & 1) == 0) P.ok = false;  // pair sides must differ
  }
  for (int w = 0; w < N_WIRES; ++w) {
    const int v = mp(phi[w]), r2 = mp(pir[w]);
    P.tvs[w] = v & 15; P.tvl[w] = v >> 4;
    P.trs[w] = r2 & 15; P.trl[w] = r2 >> 4;
    P.mrs[w] = r2 & 15; P.mrl[w] = r2 >> 4;
    if (v == 0 || r2 == 0) P.ok = false;
    if ((__builtin_popcount((unsigned)(v & r2)) & 1) == 0) P.ok = false;
  }
  return P;
}

constexpr Prog PROG = make_prog();
static_assert(PROG.ok, "Clifford tracking invariant violated");

// --------------------------------- device ------------------------------------

struct Ctx { int lane; bool s32; };
struct U2t { float ty, tx, A, s; };   // tail V = RY*RX/(cy*cx)

__device__ inline f2 fswap(f2 v) { return __builtin_shufflevector(v, v, 1, 0); }

__device__ inline float bcast(float x, int l) {
  return __int_as_float(__builtin_amdgcn_readlane(__float_as_int(x), l));
}

// fast lane xor-exchange by arbitrary mask 1..63 (probe-validated mechanisms)
// R11 A/B-established: ds_swizzle (DS pipe, overlaps VALU) beats multi-op DPP
// chains here — kernel is VALU-issue-bound. Keep DPP only for 1-op masks 1/2.
template <int VL>
__device__ inline float lxf(float x, const Ctx& cx) {
  static_assert(VL >= 1 && VL <= 63, "");
  if constexpr (VL == 1) {
    return __int_as_float(__builtin_amdgcn_update_dpp(0, __float_as_int(x), 0xB1, 0xF, 0xF, true));
  } else if constexpr (VL == 2) {
    return __int_as_float(__builtin_amdgcn_update_dpp(0, __float_as_int(x), 0x4E, 0xF, 0xF, true));
  } else if constexpr (VL < 32) {
    return __int_as_float(__builtin_amdgcn_ds_swizzle(__float_as_int(x), (VL << 10) | 0x1F));
  } else {
    float t;
#if __has_builtin(__builtin_amdgcn_permlane32_swap)
    {
      auto r = __builtin_amdgcn_permlane32_swap(__float_as_int(x), __float_as_int(x), false, false);
      t = __int_as_float(cx.s32 ? r[0] : r[1]);
    }
#else
    t = __shfl_xor(x, 32, 64);
#endif
    if constexpr ((VL & 31) != 0)
      return __int_as_float(__builtin_amdgcn_ds_swizzle(__float_as_int(t), ((VL & 31) << 10) | 0x1F));
    else
      return t;
  }
}
template <int VL>
__device__ inline f2 lxf2(f2 v, const Ctx& cx) {
  f2 r; r.x = lxf<VL>(v.x, cx); r.y = lxf<VL>(v.y, cx); return r;
}

// SAFE exchange
template <int M>
__device__ inline float sshfl(float x) { return __shfl_xor(x, M, 64); }
template <int M>
__device__ inline f2 sshfl2(f2 v) { f2 r; r.x = sshfl<M>(v.x); r.y = sshfl<M>(v.y); return r; }

template <int RL>
__device__ inline bool lpar6(const bool (&lb)[6]) {
  bool p = false;
  if constexpr (RL & 1)  p ^= lb[0];
  if constexpr (RL & 2)  p ^= lb[1];
  if constexpr (RL & 4)  p ^= lb[2];
  if constexpr (RL & 8)  p ^= lb[3];
  if constexpr (RL & 16) p ^= lb[4];
  if constexpr (RL & 32) p ^= lb[5];
  return p;
}

// ---------------- FAST gates: tau-form with generalized xor-masks ------------

template <int TY, int VS, int VL, int RS, int RL>
__device__ inline void rot_fast(f2 (&st)[16], float tau, const Ctx& cx, const bool (&lb)[6]) {
  if constexpr (TY == 2) {            // RZ: diagonal, only side parity matters
    const bool lp_ = lpar6<RL>(lb);
    const f2 tn = {tau, -tau}, tnn = {-tau, tau};
    const f2 tA = lp_ ? tnn : tn;     // slots with spar==0
    const f2 tB = lp_ ? tn : tnn;     // slots with spar==1
    #pragma unroll
    for (int j = 0; j < 16; ++j) {
      const f2 t = (__builtin_popcount((unsigned)(j & RS)) & 1) ? tB : tA;
      st[j] = st[j] + t * fswap(st[j]);
    }
  } else if constexpr (TY == 0) {     // RX: symmetric, no side needed
    const f2 tn = {tau, -tau};
    #pragma unroll
    for (int j = 0; j < 16; ++j) {
      if constexpr (VS != 0) { if (j & (VS & -VS)) continue; }  // canonical half
      const int j2 = j ^ VS;
      f2 pj, pj2;
      if constexpr (VL != 0) {
        pj = lxf2<VL>(st[j2], cx);
        if constexpr (VS != 0) pj2 = lxf2<VL>(st[j], cx);
      } else { pj = st[j2]; pj2 = st[j]; }
      st[j] = st[j] + tn * fswap(pj);
      if constexpr (VS != 0) st[j2] = st[j2] + tn * fswap(pj2);
    }
  } else {                            // RY: sign = side ? +tau : -tau
    const bool lp_ = lpar6<RL>(lb);
    const f2 tp = {tau, tau}, tm = {-tau, -tau};
    const f2 sA = lp_ ? tp : tm;      // spar==0
    const f2 sB = lp_ ? tm : tp;      // spar==1
    #pragma unroll
    for (int j = 0; j < 16; ++j) {
      if constexpr (VS != 0) { if (j & (VS & -VS)) continue; }
      const int j2 = j ^ VS;
      f2 pj, pj2;
      if constexpr (VL != 0) {
        pj = lxf2<VL>(st[j2], cx);
        if constexpr (VS != 0) pj2 = lxf2<VL>(st[j], cx);
      } else { pj = st[j2]; pj2 = st[j]; }
      const f2 s1 = (__builtin_popcount((unsigned)(j & RS)) & 1) ? sB : sA;
      st[j] = st[j] + s1 * pj;
      if constexpr (VS != 0) {
        const f2 s2_ = (__builtin_popcount((unsigned)(j2 & RS)) & 1) ? sB : sA;
        st[j2] = st[j2] + s2_ * pj2;
      }
    }
  }
}

// tail V: v00=1+iA v01=-ty-itx v10=ty-itx v11=1-iA  (A=ty*tx)
template <int VS, int VL, int RS, int RL>
__device__ inline void tail_fast(f2 (&st)[16], const U2t& u, const Ctx& cx, const bool (&lb)[6]) {
  const bool lp_ = lpar6<RL>(lb);
  const f2 TpP = {u.ty, u.ty}, TpM = {-u.ty, -u.ty};
  const f2 TsP = {u.A, -u.A},  TsM = {-u.A, u.A};
  const f2 Xs  = {u.tx, -u.tx};
  const f2 TpA = lp_ ? TpP : TpM, TpB = lp_ ? TpM : TpP;
  const f2 TsA = lp_ ? TsP : TsM, TsB = lp_ ? TsM : TsP;
  #pragma unroll
  for (int j = 0; j < 16; ++j) {
    if constexpr (VS != 0) { if (j & (VS & -VS)) continue; }
    const int j2 = j ^ VS;
    f2 pj, pj2;
    if constexpr (VL != 0) {
      pj = lxf2<VL>(st[j2], cx);
      if constexpr (VS != 0) pj2 = lxf2<VL>(st[j], cx);
    } else { pj = st[j2]; pj2 = st[j]; }
    {
      const bool sp = __builtin_popcount((unsigned)(j & RS)) & 1;
      const f2 a = st[j];
      f2 o = a + (sp ? TpB : TpA) * pj;
      o = o + (sp ? TsB : TsA) * fswap(a);
      o = o + Xs * fswap(pj);
      st[j] = o;
    }
    if constexpr (VS != 0) {
      const bool sp = __builtin_popcount((unsigned)(j2 & RS)) & 1;
      const f2 a = st[j2];
      f2 o = a + (sp ? TpB : TpA) * pj2;
      o = o + (sp ? TsB : TsA) * fswap(a);
      o = o + Xs * fswap(pj2);
      st[j2] = o;
    }
  }
}

template <int K>
__device__ inline void run_rot(f2 (&st)[16], float tc, float ts, const Ctx& cx,
                               float& scale, const bool (&lb)[6]) {
  if constexpr (K < N_OPS) {
    if constexpr (K < PROG.nrot) {
      const float c = bcast(tc, PROG.raidx[K]);
      const float s = bcast(ts, PROG.raidx[K]);
      const float tau = s * __builtin_amdgcn_rcpf(c);
      scale *= c;
      rot_fast<PROG.rty[K], PROG.rvs[K], PROG.rvl[K], PROG.rrs[K], PROG.rrl[K]>(st, tau, cx, lb);
      run_rot<K + 1>(st, tc, ts, cx, scale, lb);
    }
  }
}

template <int W>
__device__ inline void run_tail(f2 (&st)[16], const U2t& u, const Ctx& cx,
                                float& scale, const bool (&lb)[6]) {
  if constexpr (W < N_WIRES) {
    scale *= u.s;
    tail_fast<PROG.tvs[W], PROG.tvl[W], PROG.trs[W], PROG.trl[W]>(st, u, cx, lb);
    run_tail<W + 1>(st, u, cx, scale, lb);
  }
}

// encoder / head helpers (template-unrolled over wires)
template <int W>
__device__ inline void enc_lane(float& lp, const bool (&lb)[6], const float (&ec)[10], const float (&es)[10]) {
  if constexpr (W < N_WIRES) {
    if constexpr (PROG.pos[W] >= 4)
      lp *= lb[PROG.pos[W] - 4] ? es[W] : ec[W];
    enc_lane<W + 1>(lp, lb, ec, es);
  }
}
template <int W>
__device__ inline void enc_slot(float& a, int j, const float (&ec)[10], const float (&es)[10]) {
  if constexpr (W < N_WIRES) {
    if constexpr (PROG.pos[W] < 4)
      a *= ((j >> PROG.pos[W]) & 1) ? es[W] : ec[W];
    enc_slot<W + 1>(a, j, ec, es);
  }
}
template <int W>
__device__ inline void head_lane(float (&h2)[10], const bool (&lb)[6], const float (&hwv)[10]) {
  if constexpr (W < N_WIRES) {
    const bool lp_ = lpar6<PROG.mrl[W]>(lb);
    h2[W] = lp_ ? -hwv[W] : hwv[W];
    head_lane<W + 1>(h2, lb, hwv);
  }
}
template <int W>
__device__ inline void head_shared(float& L, const float (&h2)[10]) {
  if constexpr (W < N_WIRES) {
    if constexpr (PROG.mrs[W] == 0) L += h2[W];
    head_shared<W + 1>(L, h2);
  }
}
template <int W>
__device__ inline void head_slot(float& sw, int j, const float (&h2)[10]) {
  if constexpr (W < N_WIRES) {
    if constexpr (PROG.mrs[W] != 0)
      sw += (__builtin_popcount((unsigned)(j & PROG.mrs[W])) & 1) ? -h2[W] : h2[W];
    head_slot<W + 1>(sw, j, h2);
  }
}

__device__ inline void body_fast(const Ctx& cx, int b, float tc, float ts,
                                 const float* __restrict__ hw, const float* __restrict__ hb,
                                 float* __restrict__ out) {
  const int lane = cx.lane;
  const bool lb[6] = { (bool)((lane >> 0) & 1), (bool)((lane >> 1) & 1), (bool)((lane >> 2) & 1),
                       (bool)((lane >> 3) & 1), (bool)((lane >> 4) & 1), (bool)((lane >> 5) & 1) };
  U2t u;
  {
    const float cxr = bcast(tc, 40), sxr = bcast(ts, 40);
    const float cyr = bcast(tc, 41), syr = bcast(ts, 41);
    u.tx = sxr * __builtin_amdgcn_rcpf(cxr);
    u.ty = syr * __builtin_amdgcn_rcpf(cyr);
    u.A = u.ty * u.tx;
    u.s = cyr * cxr;
  }
  float ec[10], es[10];
  #pragma unroll
  for (int w = 0; w < N_WIRES; ++w) { ec[w] = bcast(tc, w); es[w] = bcast(ts, w); }
  float lpv = 1.0f;
  enc_lane<0>(lpv, lb, ec, es);
  f2 st[16];
  #pragma unroll
  for (int j = 0; j < 16; ++j) {
    float a = lpv;
    enc_slot<0>(a, j, ec, es);
    st[j] = (f2){a, 0.0f};
  }

  float scale = 1.0f;
  run_rot<0>(st, tc, ts, cx, scale, lb);
  run_tail<0>(st, u, cx, scale, lb);

  float hwv[10];
  #pragma unroll
  for (int w = 0; w < N_WIRES; ++w) hwv[w] = hw[w];
  float h2[10];
  head_lane<0>(h2, lb, hwv);
  float L = 0.0f;
  head_shared<0>(L, h2);
  float acc = 0.0f;
  #pragma unroll
  for (int j = 0; j < 16; ++j) {
    float sw = L;
    head_slot<0>(sw, j, h2);
    const f2 q = st[j] * st[j];
    acc += (q.x + q.y) * sw;
  }
  acc *= scale * scale;      // restore deferred gate scalars
  acc += lxf<1>(acc, cx);
  acc += lxf<2>(acc, cx);
  acc += lxf<4>(acc, cx);
  acc += lxf<8>(acc, cx);
  acc += lxf<16>(acc, cx);
  acc += lxf<32>(acc, cx);
  if (lane == 0) {
    const float logit = acc + hb[0] + 1.57079632679489662f;  // + SHIFT
    out[b] = 1.0f / (1.0f + expf(-logit));
  }
}

// ---------------- SAFE path (R9-proven, classic c,s form) --------------------

template <int TY, int P>
__device__ inline void gate_local_cs(f2 (&st)[16], float c, float s) {
  const f2 c2 = {c, c}, s2 = {s, s}, sn = {s, -s};
  #pragma unroll
  for (int b = 0; b < 16; ++b) {
    if ((b >> P) & 1) continue;
    const int i0 = b, i1 = b | (1 << P);
    const f2 a0 = st[i0], a1 = st[i1];
    if constexpr (TY == 0) {
      st[i0] = c2 * a0 + sn * fswap(a1);
      st[i1] = c2 * a1 + sn * fswap(a0);
    } else if constexpr (TY == 1) {
      st[i0] = c2 * a0 - s2 * a1;
      st[i1] = c2 * a1 + s2 * a0;
    } else {
      st[i0] = c2 * a0 + sn * fswap(a0);
      st[i1] = c2 * a1 - sn * fswap(a1);
    }
  }
}

template <int TY, int LB>
__device__ inline void gate_lane_cs(f2 (&st)[16], float c, float s, int lane) {
  const f2 c2 = {c, c};
  if constexpr (TY == 2) {
    const float t = ((lane >> LB) & 1) ? -s : s;
    const f2 tn = {t, -t};
    #pragma unroll
    for (int j = 0; j < 16; ++j) st[j] = c2 * st[j] + tn * fswap(st[j]);
  } else if constexpr (TY == 0) {
    const f2 sn = {s, -s};
    #pragma unroll
    for (int j = 0; j < 16; ++j) {
      const f2 p = sshfl2<(1 << LB)>(st[j]);
      st[j] = c2 * st[j] + sn * fswap(p);
    }
  } else {
    const float sg = ((lane >> LB) & 1) ? s : -s;
    const f2 sg2 = {sg, sg};
    #pragma unroll
    for (int j = 0; j < 16; ++j) {
      const f2 p = sshfl2<(1 << LB)>(st[j]);
      st[j] = c2 * st[j] + sg2 * p;
    }
  }
}

template <int CB, int TB>
__device__ inline void cnot_safe(f2 (&st)[16], int lane) {
  if constexpr (CB < 4 && TB < 4) {
    #pragma unroll
    for (int b = 0; b < 16; ++b) {
      if (((b >> CB) & 1) && !((b >> TB) & 1)) {
        const int j = b | (1 << TB);
        const f2 t = st[b]; st[b] = st[j]; st[j] = t;
      }
    }
  } else if constexpr (CB < 4) {
    constexpr int M = 1 << (TB - 4);
    #pragma unroll
    for (int b = 0; b < 16; ++b) {
      if ((b >> CB) & 1) st[b] = sshfl2<M>(st[b]);
    }
  } else if constexpr (TB < 4) {
    const bool cb = (lane >> (CB - 4)) & 1;
    #pragma unroll
    for (int b = 0; b < 16; ++b) {
      if (!((b >> TB) & 1)) {
        const int j = b | (1 << TB);
        const f2 a0 = st[b], a1 = st[j];
        st[b] = cb ? a1 : a0; st[j] = cb ? a0 : a1;
      }
    }
  } else {
    const bool cb = (lane >> (CB - 4)) & 1;
    constexpr int M = 1 << (TB - 4);
    #pragma unroll
    for (int j = 0; j < 16; ++j) {
      const f2 p = sshfl2<M>(st[j]);
      st[j] = cb ? p : st[j];
    }
  }
}

template <int K>
__device__ inline void run_safe(f2 (&st)[16], float tc, float ts, int lane) {
  if constexpr (K < NG_SAFE) {
    constexpr int ty = FULLS.type[K];
    constexpr int P0 = FULLS.p0[K];
    constexpr int P1 = FULLS.p1[K];
    constexpr int AI = FULLS.aidx[K];
    if constexpr (ty == 3) {
      cnot_safe<P0, P1>(st, lane);
    } else {
      const float c = __shfl(tc, AI, 64);
      const float s = __shfl(ts, AI, 64);
      if constexpr (P0 < 4) gate_local_cs<ty, P0>(st, c, s);
      else                  gate_lane_cs<ty, P0 - 4>(st, c, s, lane);
    }
    run_safe<K + 1>(st, tc, ts, lane);
  }
}

__device__ __attribute__((noinline))
void body_safe(int lane, int b, float tc, float ts,
               const float* __restrict__ hw, const float* __restrict__ hb,
               float* __restrict__ out) {
  float ec[N_WIRES], es[N_WIRES];
  #pragma unroll
  for (int w = 0; w < N_WIRES; ++w) { ec[w] = __shfl(tc, w, 64); es[w] = __shfl(ts, w, 64); }
  float lp = ((lane >> 0) & 1) ? es[SLW0] : ec[SLW0];
  lp *= ((lane >> 1) & 1) ? es[SLW1] : ec[SLW1];
  lp *= ((lane >> 2) & 1) ? es[SLW2] : ec[SLW2];
  lp *= ((lane >> 3) & 1) ? es[SLW3] : ec[SLW3];
  lp *= ((lane >> 4) & 1) ? es[SLW4] : ec[SLW4];
  lp *= ((lane >> 5) & 1) ? es[SLW5] : ec[SLW5];
  f2 st[16];
  #pragma unroll
  for (int sl = 0; sl < 16; ++sl) {
    float a = lp;
    a *= (sl & 1) ? es[SRW0] : ec[SRW0];
    a *= (sl & 2) ? es[SRW1] : ec[SRW1];
    a *= (sl & 4) ? es[SRW2] : ec[SRW2];
    a *= (sl & 8) ? es[SRW3] : ec[SRW3];
    st[sl] = (f2){a, 0.0f};
  }
  run_safe<0>(st, tc, ts, lane);
  float hwv[N_WIRES];
  #pragma unroll
  for (int w = 0; w < N_WIRES; ++w) hwv[w] = hw[w];
  float lw = (((lane >> 0) & 1) ? -hwv[SLW0] : hwv[SLW0])
           + (((lane >> 1) & 1) ? -hwv[SLW1] : hwv[SLW1])
           + (((lane >> 2) & 1) ? -hwv[SLW2] : hwv[SLW2])
           + (((lane >> 3) & 1) ? -hwv[SLW3] : hwv[SLW3])
           + (((lane >> 4) & 1) ? -hwv[SLW4] : hwv[SLW4])
           + (((lane >> 5) & 1) ? -hwv[SLW5] : hwv[SLW5]);
  float acc = 0.0f;
  #pragma unroll
  for (int sl = 0; sl < 16; ++sl) {
    float sw = lw;
    sw += (sl & 1) ? -hwv[SRW0] : hwv[SRW0];
    sw += (sl & 2) ? -hwv[SRW1] : hwv[SRW1];
    sw += (sl & 4) ? -hwv[SRW2] : hwv[SRW2];
    sw += (sl & 8) ? -hwv[SRW3] : hwv[SRW3];
    const f2 q = st[sl] * st[sl];
    acc += (q.x + q.y) * sw;
  }
  acc += sshfl<1>(acc);
  acc += sshfl<2>(acc);
  acc += sshfl<4>(acc);
  acc += sshfl<8>(acc);
  acc += sshfl<16>(acc);
  acc += sshfl<32>(acc);
  if (lane == 0) {
    const float logit = acc + hb[0] + 1.57079632679489662f;
    out[b] = 1.0f / (1.0f + expf(-logit));
  }
}

// ---------------------------------- kernel -----------------------------------

__global__ __launch_bounds__(256)
void qsim_kernel(const float* __restrict__ xb, const float* __restrict__ rxt,
                 const float* __restrict__ ryt, const float* __restrict__ rp,
                 const float* __restrict__ hw, const float* __restrict__ hb,
                 float* __restrict__ out, int bsz) {
  const int lane = threadIdx.x & 63;
  const int b = blockIdx.x * 4 + (threadIdx.x >> 6);  // one wave = one sample
  if (b >= bsz) return;

  float tc, ts;
  {
    float t = 0.0f;
    if (lane < 10)        t = xb[(size_t)b * 10 + lane];
    else if (lane < 40)   t = rp[lane - 10];
    else if (lane == 40)  t = rxt[0];
    else if (lane == 41)  t = ryt[0];
    float s, c;
    sincosf(0.5f * t, &s, &c);
    tc = c; ts = s;
  }

  // ---- mechanism self-test: every exchange class used by the fast path ----
  Ctx cx; cx.lane = lane; cx.s32 = false;
#if __has_builtin(__builtin_amdgcn_permlane32_swap)
  {
    auto r = __builtin_amdgcn_permlane32_swap(lane, lane, false, false);
    const bool f32 = (((lane & 32) ? r[0] : r[1]) != (lane ^ 32));
    cx.s32 = (((lane & 32) != 0) ^ f32);
  }
#endif
  bool ok = true;
  ok &= (__float_as_int(lxf<1 >(__int_as_float(lane), cx)) == (lane ^ 1));   // DPP
  ok &= (__float_as_int(lxf<2 >(__int_as_float(lane), cx)) == (lane ^ 2));   // DPP
  ok &= (__float_as_int(lxf<5 >(__int_as_float(lane), cx)) == (lane ^ 5));   // swizzle multi-bit
  ok &= (__float_as_int(lxf<16>(__int_as_float(lane), cx)) == (lane ^ 16));  // swizzle
  ok &= (__float_as_int(lxf<31>(__int_as_float(lane), cx)) == (lane ^ 31));  // swizzle full
  ok &= (__float_as_int(lxf<32>(__int_as_float(lane), cx)) == (lane ^ 32));  // permlane32
  ok &= (__float_as_int(lxf<53>(__int_as_float(lane), cx)) == (lane ^ 53));  // composite
  const bool fast = (__all((int)ok) != 0);

  if (fast) body_fast(cx, b, tc, ts, hw, hb, out);
  else      body_safe(lane, b, tc, ts, hw, hb, out);
}

// ---------------------------------- launch -----------------------------------

extern "C" void kernel_launch(void* const* d_in, const int* in_sizes, int n_in,
                              void* d_out, int out_size, void* d_ws, size_t ws_size,
                              hipStream_t stream) {
  const float* xb  = (const float*)d_in[0];
  const float* rxt = (const float*)d_in[1];
  const float* ryt = (const float*)d_in[2];
  const float* rp  = (const float*)d_in[3];
  const float* hw  = (const float*)d_in[4];
  const float* hb  = (const float*)d_in[5];
  float* out = (float*)d_out;

  const int bsz = in_sizes[0] / N_WIRES;
  const int nblk = (bsz + 3) / 4;

  hipLaunchKernelGGL(qsim_kernel, dim3(nblk), dim3(256), 0, stream,
                     xb, rxt, ryt, rp, hw, hb, out, bsz);
}